// Round 9
// baseline (201.632 us; speedup 1.0000x reference)
//
#include <hip/hip_runtime.h>
#include <cmath>

// ---------------------------------------------------------------------------
// DistanceAwareMultiheadAttention  (N=1536, E=49152, D=512, H=8, DH=64)
//
// Round 9 (byte-cutting: every replay is cold-cache because the harness
// re-poisons d_ws, so HBM bytes ~= time):
//  - eid: int32 -> uint16 (E<65536; sentinel 0xFFFF). Halves init + gathers.
//  - Opart/Lpart ELIMINATED: fixed-M0 softmax makes split-combine a plain
//    sum, so flash atomicAdds O into Obuf[N,D] and lsum into Lbuf directly
//    (3MB vs 12.6MB wr + 12.6MB rd). combine -> 3MB finalize.
//  - setup_k: pack_fw + all zero-inits fused into one partitioned-grid kernel.
//  - oddsum folded into qkvm epilogue (masked-lane shuffle + atomicAdd);
//    koddT dropped, flash/delta read kodd[n][h] directly.
//  Launches 9 -> 7. flash kept at the measured-good r6/r8 config (VGPR 84).
// ---------------------------------------------------------------------------

constexpr int Nn  = 1536;
constexpr int Dd  = 512;
constexpr int Hh  = 8;
constexpr int DHd = 64;
constexpr int SPLITS = 4;
constexpr float SCALE_F = 362.03867196751236f;   // 256*sqrt(2)
constexpr float M0 = 8.0f;                       // fixed softmax exp offset

typedef float f4 __attribute__((ext_vector_type(4)));
typedef int   i4 __attribute__((ext_vector_type(4)));
typedef unsigned short us4 __attribute__((ext_vector_type(4)));
typedef __attribute__((ext_vector_type(4))) float f32x4;
typedef __attribute__((ext_vector_type(8))) short bf16x8;

__device__ inline unsigned short bf16_rne(float x) {
    unsigned u = __float_as_uint(x);
    unsigned r = u + 0x7fff + ((u >> 16) & 1);
    return (unsigned short)(r >> 16);
}
__device__ inline float bf16_tof(unsigned short h) {
    return __uint_as_float(((unsigned)h) << 16);
}
// monotone float -> uint order encoding (for atomicMax over floats)
__device__ inline unsigned f2ord(float x) {
    unsigned b = __float_as_uint(x);
    return (b & 0x80000000u) ? ~b : (b | 0x80000000u);
}

// ------------- setup: feat/W fragment pack + ALL zero-inits (one kernel) ----
// block partition: [0,384) feat pack | [384,768) W pack | [768,3072) rel/eid16
// | [3072,3840) Obuf=0 | [3840,3852) Lbuf=0 | [3852,3876) qodd/kodd=0
// | [3876,3878) ordmax=enc(-inf)
__global__ __launch_bounds__(256) void setup_k(
    const float* __restrict__ feat,
    const float* __restrict__ Wq, const float* __restrict__ Wk, const float* __restrict__ Wv,
    unsigned short* __restrict__ pFh, unsigned short* __restrict__ pFl,
    unsigned short* __restrict__ pWh, unsigned short* __restrict__ pWl,
    float* __restrict__ rel, unsigned short* __restrict__ eid16,
    float* __restrict__ Obuf, float* __restrict__ Lbuf,
    float* __restrict__ qkodd, unsigned* __restrict__ ordmax)
{
    const int b = blockIdx.x, tid = threadIdx.x;
    if (b < 768) {
        int type = (b >= 384);
        int tg = (type ? (b - 384) : b) * 256 + tid;
        int L = tg & 63;
        int kc = (tg >> 6) & 15;
        int t10 = tg >> 10;
        const float* src;
        unsigned short *oh, *ol;
        int row, col;
        if (type == 0) {
            src = feat; oh = pFh; ol = pFl;
            row = t10 * 16 + (L & 15);
            col = kc * 32 + (L >> 4) * 8;
        } else {
            int z = t10 >> 5, nt = t10 & 31;
            src = (z == 0) ? Wq : (z == 1) ? Wk : Wv;
            oh = pWh; ol = pWl;
            row = nt * 16 + (L & 15);
            col = kc * 32 + (L >> 4) * 8;
        }
        f4 a = *(const f4*)(src + (size_t)row * Dd + col);
        f4 bb = *(const f4*)(src + (size_t)row * Dd + col + 4);
        float x[8];
        #pragma unroll
        for (int j = 0; j < 4; ++j) { x[j] = a[j]; x[4 + j] = bb[j]; }
        unsigned short hs[8], ls[8];
        #pragma unroll
        for (int j = 0; j < 8; ++j) {
            hs[j] = bf16_rne(x[j]);
            ls[j] = bf16_rne(x[j] - bf16_tof(hs[j]));
        }
        *(bf16x8*)(oh + (size_t)tg * 8) = *(bf16x8*)hs;
        *(bf16x8*)(ol + (size_t)tg * 8) = *(bf16x8*)ls;
    } else if (b < 3072) {
        size_t idx = (size_t)(b - 768) * 256 + tid;
        *(f4*)(rel + idx * 4) = (f4){0.f, 0.f, 0.f, 0.f};
        *(us4*)(eid16 + idx * 4) = (us4){0xFFFFu, 0xFFFFu, 0xFFFFu, 0xFFFFu};
    } else if (b < 3840) {
        size_t idx = (size_t)(b - 3072) * 256 + tid;
        *(f4*)(Obuf + idx * 4) = (f4){0.f, 0.f, 0.f, 0.f};
    } else if (b < 3852) {
        size_t idx = (size_t)(b - 3840) * 256 + tid;
        *(f4*)(Lbuf + idx * 4) = (f4){0.f, 0.f, 0.f, 0.f};
    } else if (b < 3876) {
        size_t idx = (size_t)(b - 3852) * 256 + tid;
        *(f4*)(qkodd + idx * 4) = (f4){0.f, 0.f, 0.f, 0.f};
    } else {
        int idx = (b - 3876) * 256 + tid;
        ordmax[idx] = 0x007FFFFFu;  // encode(-inf)
    }
}

// --------- QKV projection, MFMA, kc-pipelined, fused pack + odd-sums --------
// grid (8,24,3) block 256 = 4 waves; wave = 32 rows x 32 cols.
// Epilogue: per-wave LDS transpose; z<2: f32 Q/K store + A-frag pack + odd-col
// row-sum atomicAdd into qodd/kodd; z=2: V B-frag pack only.
__global__ __launch_bounds__(256) void qkvm_k(
    const unsigned short* __restrict__ pFh, const unsigned short* __restrict__ pFl,
    const unsigned short* __restrict__ pWh, const unsigned short* __restrict__ pWl,
    const float* __restrict__ bq, const float* __restrict__ bk, const float* __restrict__ bv,
    float* __restrict__ Qo, float* __restrict__ Ko,
    float* __restrict__ qodd, float* __restrict__ kodd,
    unsigned short* __restrict__ pQh, unsigned short* __restrict__ pQl,
    unsigned short* __restrict__ pKh, unsigned short* __restrict__ pKl,
    unsigned short* __restrict__ pVh, unsigned short* __restrict__ pVl)
{
    const int z = blockIdx.z;
    const float* __restrict__ bias = (z == 0) ? bq : (z == 1) ? bk : bv;
    const int tid = threadIdx.x;
    const int L = tid & 63, wv = tid >> 6;
    const int l15 = L & 15, quad = L >> 4;
    const int mt0 = blockIdx.y * 4 + (wv & 1) * 2;
    const int nt0 = blockIdx.x * 4 + (wv >> 1) * 2;
    __shared__ float lds[4][32][33];

    f32x4 acc[2][2];
    #pragma unroll
    for (int i = 0; i < 2; ++i)
        #pragma unroll
        for (int j = 0; j < 2; ++j) acc[i][j] = (f32x4){0.f, 0.f, 0.f, 0.f};

    bf16x8 AH[2][2], AL[2][2], BH[2][2], BL[2][2];   // [buf][i]
    auto loadset = [&](int buf, int kc) {
        #pragma unroll
        for (int i = 0; i < 2; ++i) {
            size_t ao = ((size_t)((mt0 + i) * 16 + kc)) * 512 + L * 8;
            AH[buf][i] = *(const bf16x8*)(pFh + ao);
            AL[buf][i] = *(const bf16x8*)(pFl + ao);
            size_t bo = ((size_t)((z * 32 + nt0 + i) * 16 + kc)) * 512 + L * 8;
            BH[buf][i] = *(const bf16x8*)(pWh + bo);
            BL[buf][i] = *(const bf16x8*)(pWl + bo);
        }
    };
    auto mfmaset = [&](int buf) {
        #pragma unroll
        for (int i = 0; i < 2; ++i)
            #pragma unroll
            for (int j = 0; j < 2; ++j) {
                f32x4 a = acc[i][j];
                a = __builtin_amdgcn_mfma_f32_16x16x32_bf16(AH[buf][i], BH[buf][j], a, 0, 0, 0);
                a = __builtin_amdgcn_mfma_f32_16x16x32_bf16(AH[buf][i], BL[buf][j], a, 0, 0, 0);
                a = __builtin_amdgcn_mfma_f32_16x16x32_bf16(AL[buf][i], BH[buf][j], a, 0, 0, 0);
                a = __builtin_amdgcn_mfma_f32_16x16x32_bf16(AL[buf][i], BL[buf][j], a, 0, 0, 0);
                acc[i][j] = a;
            }
    };

    loadset(0, 0);
    #pragma unroll
    for (int kc = 0; kc < 16; kc += 2) {
        loadset(1, kc + 1);
        mfmaset(0);
        if (kc + 2 < 16) loadset(0, kc + 2);
        mfmaset(1);
    }

    float o_[2][2][4];
    #pragma unroll
    for (int i = 0; i < 2; ++i)
        #pragma unroll
        for (int j = 0; j < 2; ++j) {
            float b = bias[(nt0 + j) * 16 + l15];
            #pragma unroll
            for (int reg = 0; reg < 4; ++reg) o_[i][j][reg] = acc[i][j][reg] + b;
        }
    if (z < 2) {
        float* __restrict__ outp = (z == 0) ? Qo : Ko;
        #pragma unroll
        for (int i = 0; i < 2; ++i) {
            int row0 = (mt0 + i) * 16 + quad * 4;
            #pragma unroll
            for (int j = 0; j < 2; ++j) {
                int col = (nt0 + j) * 16 + l15;
                #pragma unroll
                for (int reg = 0; reg < 4; ++reg)
                    outp[(size_t)(row0 + reg) * Dd + col] = o_[i][j][reg];
            }
        }
        // odd-col partial row sums -> qodd/kodd (cols of this wave = 32 of 64;
        // both col-half waves atomicAdd; odd col <=> l15 odd since tiles are x16)
        float* __restrict__ odst = (z == 0) ? qodd : kodd;
        const int h = blockIdx.x;
        #pragma unroll
        for (int i = 0; i < 2; ++i) {
            #pragma unroll
            for (int reg = 0; reg < 4; ++reg) {
                float v = (l15 & 1) ? (o_[i][0][reg] + o_[i][1][reg]) : 0.f;
                #pragma unroll
                for (int o = 1; o < 16; o <<= 1) v += __shfl_xor(v, o);
                if (l15 == 0) {
                    int row = (mt0 + i) * 16 + quad * 4 + reg;
                    atomicAdd(&odst[row * Hh + h], v);
                }
            }
        }
    }
    #pragma unroll
    for (int i = 0; i < 2; ++i)
        #pragma unroll
        for (int j = 0; j < 2; ++j)
            #pragma unroll
            for (int reg = 0; reg < 4; ++reg)
                lds[wv][i * 16 + quad * 4 + reg][j * 16 + l15] = o_[i][j][reg];
    // single-wave LDS round trip: DS pipe is in-order per wave, no barrier.

    const int h = blockIdx.x;   // cols [h*64, h*64+64) == head h
    if (z < 2) {
        unsigned short* __restrict__ oh = z ? pKh : pQh;
        unsigned short* __restrict__ ol = z ? pKl : pQl;
        const int kc = wv >> 1;
        const float sc = z ? 1.0f : 0.25f;      // Q pre-scaled (exact pow2)
        #pragma unroll
        for (int i = 0; i < 2; ++i) {
            float x[8]; unsigned short hs[8], ls[8];
            #pragma unroll
            for (int j2 = 0; j2 < 8; ++j2)
                x[j2] = lds[wv][i * 16 + l15][quad * 8 + j2] * sc;
            #pragma unroll
            for (int j2 = 0; j2 < 8; ++j2) {
                hs[j2] = bf16_rne(x[j2]);
                ls[j2] = bf16_rne(x[j2] - bf16_tof(hs[j2]));
            }
            size_t off = ((size_t)((h * 96 + mt0 + i) * 2 + kc)) * 512 + L * 8;
            *(bf16x8*)(oh + off) = *(bf16x8*)hs;
            *(bf16x8*)(ol + off) = *(bf16x8*)ls;
        }
    } else {
        const int rc = blockIdx.y * 2 + (wv & 1);
        #pragma unroll
        for (int dtl = 0; dtl < 2; ++dtl) {
            int dt = (wv >> 1) * 2 + dtl;
            float x[8]; unsigned short hs[8], ls[8];
            #pragma unroll
            for (int j2 = 0; j2 < 8; ++j2)
                x[j2] = lds[wv][quad * 8 + j2][dtl * 16 + l15];
            #pragma unroll
            for (int j2 = 0; j2 < 8; ++j2) {
                hs[j2] = bf16_rne(x[j2]);
                ls[j2] = bf16_rne(x[j2] - bf16_tof(hs[j2]));
            }
            size_t off = ((size_t)((h * 48 + rc) * 4 + dt)) * 512 + L * 8;
            *(bf16x8*)(pVh + off) = *(bf16x8*)hs;
            *(bf16x8*)(pVl + off) = *(bf16x8*)ls;
        }
    }
}

// ----------------- scatter (with inline int64/int32 detect) -----------------
__global__ __launch_bounds__(256) void scatter_k(
    const int* __restrict__ raw, const float* __restrict__ attr,
    float* __restrict__ rel, unsigned short* __restrict__ eid16,
    int* __restrict__ idxn, int E)
{
    int e = blockIdx.x * 256 + threadIdx.x;
    if (e >= E) return;
    int acc = 0;
    #pragma unroll
    for (int i = 0; i < 16; ++i) acc |= raw[2 * i + 1];
    int s, t;
    if (acc == 0) { s = raw[2 * e]; t = raw[2 * (E + e)]; }   // int64 low words
    else          { s = raw[e];     t = raw[E + e]; }          // plain int32
    idxn[e] = s; idxn[E + e] = t;
    size_t off = (size_t)s * Nn + t;
    atomicAdd(rel + off, attr[e] * SCALE_F);
    eid16[off] = (unsigned short)e;  // dup edges: same (s,t) -> same delta
}

// ------------------- per-edge, per-head logit corrections -------------------
__global__ __launch_bounds__(256) void delta_k(
    const int* __restrict__ idxn, const float* __restrict__ rel,
    const float* __restrict__ Q, const float* __restrict__ K,
    const float* __restrict__ qodd, const float* __restrict__ kodd,
    float* __restrict__ delta8, int E)
{
    int t = blockIdx.x * 256 + threadIdx.x;
    if (t >= E * Hh) return;
    int e = t >> 3, h = t & 7;
    int qi = idxn[e], ri = idxn[E + e];
    float x = rel[(size_t)qi * Nn + ri];
    const float* qrow = Q + (size_t)qi * Dd + h * DHd;
    const float* krow = K + (size_t)ri * Dd + h * DHd;
    float acc = 0.f;
    #pragma unroll
    for (int i = 0; i < 32; i += 2) {
        float dd0 = 0.15915494309189535f * __builtin_amdgcn_exp2f(-0.4152410118609203f * (float)i);
        float dd1 = 0.15915494309189535f * __builtin_amdgcn_exp2f(-0.4152410118609203f * (float)(i + 1));
        float r0 = x * dd0; r0 -= floorf(r0);
        float r1 = x * dd1; r1 -= floorf(r1);
        float s0 = __builtin_amdgcn_sinf(r0), c0 = __builtin_amdgcn_cosf(r0);
        float s1 = __builtin_amdgcn_sinf(r1), c1 = __builtin_amdgcn_cosf(r1);
        f4 q4 = *(const f4*)(qrow + 2 * i);
        f4 k4 = *(const f4*)(krow + 2 * i);
        acc += (q4[0] + k4[0]) * s0 + (q4[1] + k4[1]) * c0
             + (q4[2] + k4[2]) * s1 + (q4[3] + k4[3]) * c1;
    }
    delta8[(size_t)e * Hh + h] = 0.125f * (acc - qodd[qi * Hh + h] - kodd[ri * Hh + h]);
}

// -------- flash attention: no-max softmax, K dbuf, atomic O epilogue --------
__global__ __launch_bounds__(64, 3) void flash7_k(
    const unsigned short* __restrict__ pQh, const unsigned short* __restrict__ pQl,
    const unsigned short* __restrict__ pKh, const unsigned short* __restrict__ pKl,
    const unsigned short* __restrict__ pVh, const unsigned short* __restrict__ pVl,
    const unsigned short* __restrict__ eid16, const float* __restrict__ delta8,
    const float* __restrict__ kodd,
    float* __restrict__ Obuf, float* __restrict__ Lbuf)
{
    const int qt = blockIdx.x, h = blockIdx.y, s = blockIdx.z;
    const int L = threadIdx.x, quad = L >> 4, l15 = L & 15;
    const int q0 = qt * 16;
    __shared__ unsigned short phi[16][80];
    __shared__ unsigned short plo[16][80];

    bf16x8 qh[2], ql[2];
    #pragma unroll
    for (int kc = 0; kc < 2; ++kc) {
        size_t off = ((size_t)((h * 96 + qt) * 2 + kc)) * 512 + L * 8;
        qh[kc] = *(const bf16x8*)(pQh + off);
        ql[kc] = *(const bf16x8*)(pQl + off);
    }

    f32x4 O[4];
    float lsum[4];
    #pragma unroll
    for (int r = 0; r < 4; ++r) { lsum[r] = 0.f; O[r] = (f32x4){0.f, 0.f, 0.f, 0.f}; }

    const int NT = 24 / SPLITS;         // 6 r-tiles per split
    const int Tbase = s * NT;

    bf16x8 kh0[4], kh1[4], kl0[4], kl1[4];
    {
        const int r0 = Tbase * 64;
        #pragma unroll
        for (int nt = 0; nt < 4; ++nt) {
            size_t b0 = ((size_t)((h * 96 + (r0 >> 4) + nt) * 2)) * 512 + L * 8;
            kh0[nt] = *(const bf16x8*)(pKh + b0);
            kh1[nt] = *(const bf16x8*)(pKh + b0 + 512);
            kl0[nt] = *(const bf16x8*)(pKl + b0);
            kl1[nt] = *(const bf16x8*)(pKl + b0 + 512);
        }
    }

    float kvcur[4], dcur[16];
    {
        const int r0 = Tbase * 64;
        int ecur[16];
        #pragma unroll
        for (int nt = 0; nt < 4; ++nt) {
            kvcur[nt] = 0.125f * kodd[(size_t)(r0 + nt * 16 + l15) * Hh + h];
            #pragma unroll
            for (int reg = 0; reg < 4; ++reg) {
                unsigned short uv = eid16[(size_t)(q0 + quad * 4 + reg) * Nn + r0 + nt * 16 + l15];
                ecur[nt * 4 + reg] = (uv == 0xFFFFu) ? -1 : (int)uv;
            }
        }
        #pragma unroll
        for (int i = 0; i < 16; ++i) {
            int e = ecur[i];
            float d = delta8[(size_t)(e < 0 ? 0 : e) * Hh + h];
            dcur[i] = (e >= 0) ? d : 0.f;
        }
    }

    for (int T = 0; T < NT; ++T) {
        const int r0 = (Tbase + T) * 64;
        const bool more = (T + 1 < NT);

        int   enxt[16];
        float kvnxt[4];
        if (more) {
            const int r1 = r0 + 64;
            #pragma unroll
            for (int nt = 0; nt < 4; ++nt) {
                kvnxt[nt] = 0.125f * kodd[(size_t)(r1 + nt * 16 + l15) * Hh + h];
                #pragma unroll
                for (int reg = 0; reg < 4; ++reg) {
                    unsigned short uv = eid16[(size_t)(q0 + quad * 4 + reg) * Nn + r1 + nt * 16 + l15];
                    enxt[nt * 4 + reg] = (uv == 0xFFFFu) ? -1 : (int)uv;
                }
            }
        }

        bf16x8 vh0[4], vh1[4], vl0[4], vl1[4];
        #pragma unroll
        for (int dt = 0; dt < 4; ++dt) {
            size_t vb = ((size_t)((h * 48 + (r0 >> 5)) * 4 + dt)) * 512 + L * 8;
            vh0[dt] = *(const bf16x8*)(pVh + vb);
            vh1[dt] = *(const bf16x8*)(pVh + vb + 2048);
            vl0[dt] = *(const bf16x8*)(pVl + vb);
            vl1[dt] = *(const bf16x8*)(pVl + vb + 2048);
        }

        f32x4 S[4];
        #pragma unroll
        for (int nt = 0; nt < 4; ++nt) {
            f32x4 a = {0.f, 0.f, 0.f, 0.f};
            a = __builtin_amdgcn_mfma_f32_16x16x32_bf16(qh[0], kh0[nt], a, 0, 0, 0);
            a = __builtin_amdgcn_mfma_f32_16x16x32_bf16(qh[1], kh1[nt], a, 0, 0, 0);
            a = __builtin_amdgcn_mfma_f32_16x16x32_bf16(qh[0], kl0[nt], a, 0, 0, 0);
            a = __builtin_amdgcn_mfma_f32_16x16x32_bf16(qh[1], kl1[nt], a, 0, 0, 0);
            a = __builtin_amdgcn_mfma_f32_16x16x32_bf16(ql[0], kh0[nt], a, 0, 0, 0);
            a = __builtin_amdgcn_mfma_f32_16x16x32_bf16(ql[1], kh1[nt], a, 0, 0, 0);
            S[nt] = a;
        }

        if (more) {
            const int r1 = r0 + 64;
            #pragma unroll
            for (int nt = 0; nt < 4; ++nt) {
                size_t b0 = ((size_t)((h * 96 + (r1 >> 4) + nt) * 2)) * 512 + L * 8;
                kh0[nt] = *(const bf16x8*)(pKh + b0);
                kh1[nt] = *(const bf16x8*)(pKh + b0 + 512);
                kl0[nt] = *(const bf16x8*)(pKl + b0);
                kl1[nt] = *(const bf16x8*)(pKl + b0 + 512);
            }
        }

        #pragma unroll
        for (int reg = 0; reg < 4; ++reg) {
            float p[4];
            #pragma unroll
            for (int nt = 0; nt < 4; ++nt) {
                p[nt] = __expf(S[nt][reg] + kvcur[nt] + dcur[nt * 4 + reg] - M0);
                lsum[reg] += p[nt];
                unsigned short hi = bf16_rne(p[nt]);
                phi[quad * 4 + reg][nt * 16 + l15] = hi;
                plo[quad * 4 + reg][nt * 16 + l15] = bf16_rne(p[nt] - bf16_tof(hi));
            }
        }

        bf16x8 ph[2], pl[2];
        #pragma unroll
        for (int kc2 = 0; kc2 < 2; ++kc2) {
            ph[kc2] = *(const bf16x8*)&phi[l15][kc2 * 32 + quad * 8];
            pl[kc2] = *(const bf16x8*)&plo[l15][kc2 * 32 + quad * 8];
        }

        #pragma unroll
        for (int dt = 0; dt < 4; ++dt) {
            f32x4 a = O[dt];
            a = __builtin_amdgcn_mfma_f32_16x16x32_bf16(ph[0], vh0[dt], a, 0, 0, 0);
            a = __builtin_amdgcn_mfma_f32_16x16x32_bf16(ph[1], vh1[dt], a, 0, 0, 0);
            a = __builtin_amdgcn_mfma_f32_16x16x32_bf16(ph[0], vl0[dt], a, 0, 0, 0);
            a = __builtin_amdgcn_mfma_f32_16x16x32_bf16(ph[1], vl1[dt], a, 0, 0, 0);
            a = __builtin_amdgcn_mfma_f32_16x16x32_bf16(pl[0], vh0[dt], a, 0, 0, 0);
            a = __builtin_amdgcn_mfma_f32_16x16x32_bf16(pl[1], vh1[dt], a, 0, 0, 0);
            O[dt] = a;
        }

        if (more) {
            #pragma unroll
            for (int i = 0; i < 16; ++i) {
                int e = enxt[i];
                float d = delta8[(size_t)(e < 0 ? 0 : e) * Hh + h];
                dcur[i] = (e >= 0) ? d : 0.f;
            }
            #pragma unroll
            for (int nt = 0; nt < 4; ++nt) kvcur[nt] = kvnxt[nt];
        }
    }

    #pragma unroll
    for (int reg = 0; reg < 4; ++reg) {
        #pragma unroll
        for (int o = 1; o < 16; o <<= 1) lsum[reg] += __shfl_xor(lsum[reg], o);
    }

    // ---- atomic accumulate into dense Obuf / Lbuf (plain sums over splits) --
    #pragma unroll
    for (int dt = 0; dt < 4; ++dt)
        #pragma unroll
        for (int reg = 0; reg < 4; ++reg)
            atomicAdd(&Obuf[(size_t)(q0 + quad * 4 + reg) * Dd + h * DHd + dt * 16 + l15],
                      O[dt][reg]);
    if (l15 == 0) {
        #pragma unroll
        for (int reg = 0; reg < 4; ++reg)
            atomicAdd(&Lbuf[(size_t)h * Nn + q0 + quad * 4 + reg], lsum[reg]);
    }
}

// ---------- finalize: divide by lsum + maxpool via ordered atomicMax --------
__global__ __launch_bounds__(256) void finalize_mp_k(
    const float* __restrict__ Obuf, const float* __restrict__ Lbuf,
    unsigned* __restrict__ ordmax)
{
    const int b = blockIdx.x;
    const int t = threadIdx.x;
    const int cg = (t & 127) * 4;
    const int h = cg >> 6;
    const int rh = t >> 7;
    f4 mx = {-3.0e38f, -3.0e38f, -3.0e38f, -3.0e38f};
    for (int r = 0; r < 8; ++r) {
        int q = b * 16 + rh * 8 + r;
        float inv = 1.0f / Lbuf[(size_t)h * Nn + q];
        f4 ov = *(const f4*)(Obuf + (size_t)q * Dd + cg);
        #pragma unroll
        for (int c = 0; c < 4; ++c) mx[c] = fmaxf(mx[c], ov[c] * inv);
    }
    #pragma unroll
    for (int c = 0; c < 4; ++c) atomicMax(&ordmax[cg + c], f2ord(mx[c]));
}

__global__ void decode_k(const unsigned* __restrict__ ordmax, float* __restrict__ outp)
{
    int t = blockIdx.x * 256 + threadIdx.x;
    if (t >= Dd) return;
    unsigned u = ordmax[t];
    outp[t] = (u & 0x80000000u) ? __uint_as_float(u ^ 0x80000000u) : __uint_as_float(~u);
}

// ---------------------------------------------------------------------------
extern "C" void kernel_launch(void* const* d_in, const int* in_sizes, int n_in,
                              void* d_out, int out_size, void* d_ws, size_t ws_size,
                              hipStream_t stream)
{
    const float* feat   = (const float*)d_in[0];
    const int*   rawidx = (const int*)d_in[1];
    const float* attr   = (const float*)d_in[2];
    const float* Wq = (const float*)d_in[4];
    const float* bq = (const float*)d_in[5];
    const float* Wk = (const float*)d_in[6];
    const float* bk = (const float*)d_in[7];
    const float* Wv = (const float*)d_in[8];
    const float* bv = (const float*)d_in[9];
    float* outp = (float*)d_out;
    const int E = in_sizes[2];

    const size_t ND_ = (size_t)Nn * Dd;            // 786432
    const size_t NN_ = (size_t)Nn * Nn;            // 2359296
    const size_t PK_ = (size_t)Hh * 96 * 2 * 512;  // 786432 bf16 per pack array
    float* ws    = (float*)d_ws;
    float* Q     = ws;                              // 786432 f
    float* K     = Q + ND_;                         // 786432 f
    unsigned short* pFh = (unsigned short*)(K + ND_);   // 4 x 786432 shorts
    unsigned short* pFl = pFh + PK_;
    unsigned short* pWh = pFl + PK_;
    unsigned short* pWl = pWh + PK_;
    float* rel   = (float*)(pWl + PK_);             // 2359296 f
    unsigned short* eid16 = (unsigned short*)(rel + NN_);  // 2359296 shorts
    float* delta8 = (float*)(eid16 + NN_);          // E*Hh f
    float* qodd  = delta8 + (size_t)E * Hh;         // 12288 f  (contiguous with
    float* kodd  = qodd + (size_t)Nn * Hh;          //  kodd: zeroed together)
    int*   idxn  = (int*)(kodd + (size_t)Nn * Hh);  // 2E ints
    unsigned short* pQh = (unsigned short*)(idxn + 2 * E);
    unsigned short* pQl = pQh + PK_;
    unsigned short* pKh = pQl + PK_;
    unsigned short* pKl = pKh + PK_;
    unsigned short* pVh = pKl + PK_;
    unsigned short* pVl = pVh + PK_;
    float* Obuf  = (float*)(pVl + PK_);             // 786432 f
    float* Lbuf  = Obuf + ND_;                      // 12288 f
    unsigned* ordmax = (unsigned*)(Lbuf + (size_t)Hh * Nn);  // 512 u

    setup_k<<<3878, 256, 0, stream>>>(feat, Wq, Wk, Wv, pFh, pFl, pWh, pWl,
                                      rel, eid16, Obuf, Lbuf, qodd, ordmax);
    qkvm_k<<<dim3(8, 24, 3), 256, 0, stream>>>(pFh, pFl, pWh, pWl, bq, bk, bv,
                                               Q, K, qodd, kodd,
                                               pQh, pQl, pKh, pKl, pVh, pVl);
    scatter_k<<<(E + 255) / 256, 256, 0, stream>>>(rawidx, attr, rel, eid16, idxn, E);
    delta_k<<<(E * Hh + 255) / 256, 256, 0, stream>>>(idxn, rel, Q, K, qodd, kodd, delta8, E);
    flash7_k<<<dim3(96, 8, SPLITS), 64, 0, stream>>>(pQh, pQl, pKh, pKl, pVh, pVl,
                                                     eid16, delta8, kodd, Obuf, Lbuf);
    finalize_mp_k<<<96, 256, 0, stream>>>(Obuf, Lbuf, ordmax);
    decode_k<<<(Dd + 255) / 256, 256, 0, stream>>>(ordmax, outp);
}